// Round 1
// baseline (485.816 us; speedup 1.0000x reference)
//
#include <hip/hip_runtime.h>
#include <math.h>

#define N_TOTAL 8192
#define HALF    4096
#define EMBED   192
#define TILE    64
#define NT      (N_TOTAL / TILE)   // 128 tiles per dim
#define KC      96                 // K-chunk (2 chunks of 96 = 192)
#define PADK    100                // padded LDS row stride (floats), 400B = 16B-aligned

// ---------------- ws layout ----------------
// [0]   double sumsq_all
// [8]   double acc (signed kernel sum)
// [16]  float  colsum[192]
// [784] float  inv_c  ( = 1/(16*bandwidth) )
// [800] float  sq[8192] (indexed by x-row)

__device__ __forceinline__ int total_to_xrow(int g) {
    return (g < HALF) ? (2 * g) : (2 * (g - HALF) + 1);
}

// Pass 1: per-row sum of squares + column sums + total sum of squares.
__global__ __launch_bounds__(256) void row_stats(
    const float* __restrict__ x, float* __restrict__ sq,
    float* __restrict__ colsum, double* __restrict__ sumsq_all) {
    __shared__ float ls_col[EMBED];
    __shared__ float ls_sq[8];
    int t = threadIdx.x;
    if (t < EMBED) ls_col[t] = 0.f;
    __syncthreads();

    int row  = blockIdx.x * 8 + (t >> 5);   // 1024 blocks * 8 rows
    int lane = t & 31;
    const float* xr = x + row * EMBED;
    float s = 0.f;
    float vals[6];
#pragma unroll
    for (int m = 0; m < 6; ++m) {
        float v = xr[lane + 32 * m];
        vals[m] = v;
        s += v * v;
    }
#pragma unroll
    for (int off = 16; off; off >>= 1) s += __shfl_down(s, off, 32);
    if (lane == 0) { sq[row] = s; ls_sq[t >> 5] = s; }
#pragma unroll
    for (int m = 0; m < 6; ++m) atomicAdd(&ls_col[lane + 32 * m], vals[m]);
    __syncthreads();
    if (t < EMBED) atomicAdd(&colsum[t], ls_col[t]);
    if (t == 0) {
        double b = 0.0;
#pragma unroll
        for (int m = 0; m < 8; ++m) b += (double)ls_sq[m];
        atomicAdd(sumsq_all, b);
    }
}

// Pass 2: bandwidth via closed form (clamp effect is O(1e-10) relative).
__global__ void finalize_bw(const float* __restrict__ colsum,
                            const double* __restrict__ sumsq_all,
                            float* __restrict__ inv_c) {
    if (threadIdx.x == 0 && blockIdx.x == 0) {
        double s2 = 0.0;
        for (int k = 0; k < EMBED; ++k) {
            double c = (double)colsum[k];
            s2 += c * c;
        }
        double n = (double)N_TOTAL;
        double sumL2 = 2.0 * n * (*sumsq_all) - 2.0 * s2;
        double bw = sumL2 / (n * n - n) / 4.0;   // / KERNEL_MUL^(KERNEL_NUM//2)
        *inv_c = (float)(1.0 / (16.0 * bw));
    }
}

// Pass 3: fused Gram + multi-scale Gaussian + signed reduction (upper triangle).
__global__ __launch_bounds__(256, 2) void mmd_main(
    const float* __restrict__ x, const float* __restrict__ sq,
    const float* __restrict__ inv_c, double* __restrict__ acc_out) {
    int bi = blockIdx.y, bj = blockIdx.x;
    if (bi > bj) return;   // triangle only

    __shared__ float As[TILE][PADK];
    __shared__ float Bs[TILE][PADK];
    __shared__ double wsum[4];

    int t  = threadIdx.x;
    int tx = t & 15, ty = t >> 4;
    int I0 = bi * TILE, J0 = bj * TILE;

    float accv[4][4] = {};
    const float cc = *inv_c;

    for (int kc0 = 0; kc0 < EMBED; kc0 += KC) {
        // stage 64 rows x 96 floats for A and B (1536 float4 each, 6 per thread)
        for (int s = t; s < TILE * (KC / 4); s += 256) {
            int r  = s / (KC / 4);
            int c4 = s % (KC / 4);
            int xrA = total_to_xrow(I0 + r);
            int xrB = total_to_xrow(J0 + r);
            *(float4*)&As[r][c4 * 4] = *(const float4*)(x + (size_t)xrA * EMBED + kc0 + c4 * 4);
            *(float4*)&Bs[r][c4 * 4] = *(const float4*)(x + (size_t)xrB * EMBED + kc0 + c4 * 4);
        }
        __syncthreads();

#pragma unroll
        for (int kk = 0; kk < KC; kk += 4) {
            float4 av[4], bv[4];
#pragma unroll
            for (int i = 0; i < 4; ++i) av[i] = *(const float4*)&As[ty + 16 * i][kk];
#pragma unroll
            for (int j = 0; j < 4; ++j) bv[j] = *(const float4*)&Bs[tx + 16 * j][kk];
#pragma unroll
            for (int i = 0; i < 4; ++i)
#pragma unroll
                for (int j = 0; j < 4; ++j)
                    accv[i][j] += av[i].x * bv[j].x + av[i].y * bv[j].y +
                                  av[i].z * bv[j].z + av[i].w * bv[j].w;
        }
        __syncthreads();
    }

    // epilogue: L2 -> 5-scale Gaussian via u-powers -> signed/weighted sum
    float sqi[4], sqj[4];
#pragma unroll
    for (int i = 0; i < 4; ++i) sqi[i] = sq[total_to_xrow(I0 + ty + 16 * i)];
#pragma unroll
    for (int j = 0; j < 4; ++j) sqj[j] = sq[total_to_xrow(J0 + tx + 16 * j)];

    float sgn  = ((I0 < HALF) == (J0 < HALF)) ? 1.f : -1.f;
    bool  diag = (bi == bj);
    float tsum = 0.f;
#pragma unroll
    for (int i = 0; i < 4; ++i) {
#pragma unroll
        for (int j = 0; j < 4; ++j) {
            int gi = I0 + ty + 16 * i;
            int gj = J0 + tx + 16 * j;
            float w = diag ? ((gi < gj) ? 2.f : (gi == gj ? 1.f : 0.f)) : 2.f;
            float L2 = sqi[i] + sqj[j] - 2.f * accv[i][j];
            L2 = fmaxf(L2, 0.f);
            float u   = __expf(-L2 * cc);
            float u2  = u * u;
            float u4  = u2 * u2;
            float u8  = u4 * u4;
            float u16 = u8 * u8;
            tsum += w * (u + u2 + u4 + u8 + u16);
        }
    }
    tsum *= sgn;

#pragma unroll
    for (int off = 32; off; off >>= 1) tsum += __shfl_down(tsum, off, 64);
    int wid = t >> 6, lane = t & 63;
    if (lane == 0) wsum[wid] = (double)tsum;
    __syncthreads();
    if (t == 0) {
        double b = wsum[0] + wsum[1] + wsum[2] + wsum[3];
        atomicAdd(acc_out, b);
    }
}

__global__ void finalize_loss(const double* __restrict__ acc, float* __restrict__ out) {
    if (threadIdx.x == 0 && blockIdx.x == 0)
        out[0] = (float)(*acc / ((double)HALF * (double)HALF));
}

extern "C" void kernel_launch(void* const* d_in, const int* in_sizes, int n_in,
                              void* d_out, int out_size, void* d_ws, size_t ws_size,
                              hipStream_t stream) {
    const float* x = (const float*)d_in[0];   // label / genre_label unused by reference

    double* d_sumsq  = (double*)d_ws;
    double* d_acc    = (double*)d_ws + 1;
    float*  d_colsum = (float*)((char*)d_ws + 16);
    float*  d_invc   = (float*)((char*)d_ws + 16 + EMBED * 4);
    float*  d_sq     = (float*)((char*)d_ws + 800);

    hipMemsetAsync(d_ws, 0, 800, stream);   // zero accumulators (ws is re-poisoned 0xAA)

    row_stats<<<N_TOTAL / 8, 256, 0, stream>>>(x, d_sq, d_colsum, d_sumsq);
    finalize_bw<<<1, 1, 0, stream>>>(d_colsum, d_sumsq, d_invc);
    dim3 grid(NT, NT);
    mmd_main<<<grid, 256, 0, stream>>>(x, d_sq, d_invc, d_acc);
    finalize_loss<<<1, 1, 0, stream>>>(d_acc, (float*)d_out);
}

// Round 2
// 132.106 us; speedup vs baseline: 3.6775x; 3.6775x over previous
//
#include <hip/hip_runtime.h>
#include <math.h>

#define N_TOTAL 8192
#define HALF    4096
#define EMBED   192
#define BT      128                 // block tile (128x128 pairs per block)
#define NT      (N_TOTAL / BT)      // 64 tiles per dim
#define NBLK    (NT * (NT + 1) / 2) // 2080 upper-triangle blocks
#define KC      96                  // K staged in 2 chunks of 96
#define PADK    104                 // LDS row stride in bf16 elems: 208B = 52 words -> 2-way only

typedef short     bf16x8 __attribute__((ext_vector_type(8)));
typedef float     f32x4  __attribute__((ext_vector_type(4)));

// ---------------- ws layout (bytes) ----------------
// [0]     double sumsq_all
// [8]     double acc (signed kernel sum)
// [16]    float  colsum[192]
// [784]   float  inv_c  ( = 1/(16*bandwidth) )
// [800]   float  sq[8192]        (TOTAL-order row sumsq)
// [33568] ushort xb[8192*192]    (TOTAL-order bf16 copy of x)

__device__ __forceinline__ unsigned pack2_bf16(float a, float b) {
    unsigned ua = __float_as_uint(a), ub = __float_as_uint(b);
    unsigned ha = (ua + 0x7FFFu + ((ua >> 16) & 1u)) >> 16;   // RNE
    unsigned hb = (ub + 0x7FFFu + ((ub >> 16) & 1u)) >> 16;
    return ha | (hb << 16);
}

// Pass 1: per-row sumsq (total-order) + column sums + total sumsq.
// 256 blocks x 32 rows: global atomic chain depth per colsum address = 256.
__global__ __launch_bounds__(256) void row_stats(
    const float* __restrict__ x, float* __restrict__ sq,
    float* __restrict__ colsum, double* __restrict__ sumsq_all) {
    __shared__ float  ls_col[EMBED];
    __shared__ double ls_sq[8];
    int t = threadIdx.x, w = t >> 5, lane = t & 31;
    if (t < EMBED) ls_col[t] = 0.f;
    __syncthreads();

    double wsq = 0.0;
#pragma unroll
    for (int q = 0; q < 4; ++q) {
        int r = blockIdx.x * 32 + w * 4 + q;
        const float* xr = x + (size_t)r * EMBED;
        float s = 0.f, vals[6];
#pragma unroll
        for (int m = 0; m < 6; ++m) {
            float v = xr[lane + 32 * m];
            vals[m] = v;
            s += v * v;
        }
#pragma unroll
        for (int off = 16; off; off >>= 1) s += __shfl_down(s, off, 32);
        if (lane == 0) {
            int g = (r & 1) ? (HALF + (r >> 1)) : (r >> 1);
            sq[g] = s;
            wsq += (double)s;
        }
#pragma unroll
        for (int m = 0; m < 6; ++m) atomicAdd(&ls_col[lane + 32 * m], vals[m]);
    }
    if (lane == 0) ls_sq[w] = wsq;
    __syncthreads();
    if (t < EMBED) atomicAdd(&colsum[t], ls_col[t]);
    if (t == 0) {
        double b = 0.0;
#pragma unroll
        for (int m = 0; m < 8; ++m) b += ls_sq[m];
        atomicAdd(sumsq_all, b);
    }
}

// Pass 1b: fp32 -> bf16 convert, reordered into "total" row order.
__global__ __launch_bounds__(256) void convert_bf16(
    const float* __restrict__ x, unsigned short* __restrict__ xb) {
    int u = blockIdx.x * 256 + threadIdx.x;  // 0 .. 8192*24-1
    int r = u / 24;
    int c = (u - r * 24) * 8;
    int g = (r & 1) ? (HALF + (r >> 1)) : (r >> 1);
    const float* src = x + (size_t)r * EMBED + c;
    float4 f0 = *(const float4*)src;
    float4 f1 = *(const float4*)(src + 4);
    uint4 o;
    o.x = pack2_bf16(f0.x, f0.y);
    o.y = pack2_bf16(f0.z, f0.w);
    o.z = pack2_bf16(f1.x, f1.y);
    o.w = pack2_bf16(f1.z, f1.w);
    *(uint4*)(xb + (size_t)g * EMBED + c) = o;
}

// Pass 2: bandwidth via closed form (clamp effect is O(1e-10) relative).
__global__ void finalize_bw(const float* __restrict__ colsum,
                            const double* __restrict__ sumsq_all,
                            float* __restrict__ inv_c) {
    if (threadIdx.x == 0 && blockIdx.x == 0) {
        double s2 = 0.0;
        for (int k = 0; k < EMBED; ++k) {
            double c = (double)colsum[k];
            s2 += c * c;
        }
        double n = (double)N_TOTAL;
        double sumL2 = 2.0 * n * (*sumsq_all) - 2.0 * s2;
        double bw = sumL2 / (n * n - n) / 4.0;   // / KERNEL_MUL^(KERNEL_NUM//2)
        *inv_c = (float)(1.0 / (16.0 * bw));
    }
}

// Pass 3: MFMA Gram + fused 5-scale Gaussian epilogue, upper triangle.
// 4 waves/block; wave (wy,wx) computes a 64x64 sub-tile as 4x4 of 16x16x32 bf16 MFMA.
__global__ __launch_bounds__(256, 3) void mmd_mfma(
    const unsigned short* __restrict__ xb, const float* __restrict__ sq,
    const float* __restrict__ inv_c, double* __restrict__ acc_out) {
    // decode upper-triangle block index
    int id = blockIdx.x, bi = 0;
    while (id >= NT - bi) { id -= NT - bi; ++bi; }
    int bj = bi + id;
    int I0 = bi * BT, J0 = bj * BT;

    __shared__ unsigned short As[BT][PADK];
    __shared__ unsigned short Bs[BT][PADK];
    __shared__ double wred[4];

    int t = threadIdx.x, lane = t & 63, wid = t >> 6;
    int wy = (wid >> 1) * 64, wx = (wid & 1) * 64;
    int lo = lane & 15, kg = lane >> 4;   // fragment row / k-group

    f32x4 acc[4][4];
#pragma unroll
    for (int i = 0; i < 4; ++i)
#pragma unroll
        for (int j = 0; j < 4; ++j) acc[i][j] = (f32x4)(0.f);

    for (int kc0 = 0; kc0 < EMBED; kc0 += KC) {
        // stage A and B chunks: 2 tiles * 128 rows * 12 x (16B) = 3072 transfers
        for (int s = t; s < 2 * BT * (KC / 8); s += 256) {
            int tile = s / (BT * (KC / 8));
            int rem  = s - tile * (BT * (KC / 8));
            int r    = rem / (KC / 8);
            int c    = (rem - r * (KC / 8)) * 8;
            int g    = (tile ? J0 : I0) + r;
            uint4 v  = *(const uint4*)(xb + (size_t)g * EMBED + kc0 + c);
            unsigned short* dst = tile ? &Bs[r][c] : &As[r][c];
            *(uint4*)dst = v;
        }
        __syncthreads();
#pragma unroll
        for (int kk = 0; kk < KC; kk += 32) {
            bf16x8 a[4], b[4];
#pragma unroll
            for (int i = 0; i < 4; ++i) a[i] = *(const bf16x8*)&As[wy + i * 16 + lo][kk + kg * 8];
#pragma unroll
            for (int j = 0; j < 4; ++j) b[j] = *(const bf16x8*)&Bs[wx + j * 16 + lo][kk + kg * 8];
#pragma unroll
            for (int i = 0; i < 4; ++i)
#pragma unroll
                for (int j = 0; j < 4; ++j)
                    acc[i][j] = __builtin_amdgcn_mfma_f32_16x16x32_bf16(a[i], b[j], acc[i][j], 0, 0, 0);
        }
        __syncthreads();
    }

    // epilogue: C/D layout col=lane&15, row=(lane>>4)*4+reg (m89-verified)
    const float cc = *inv_c;
    int gi0 = I0 + wy + kg * 4;
    int gj0 = J0 + wx + lo;
    float sqi[4][4], sqj[4];
#pragma unroll
    for (int i = 0; i < 4; ++i)
#pragma unroll
        for (int r = 0; r < 4; ++r) sqi[i][r] = sq[gi0 + i * 16 + r];
#pragma unroll
    for (int j = 0; j < 4; ++j) sqj[j] = sq[gj0 + j * 16];

    float sgn  = ((bi < NT / 2) == (bj < NT / 2)) ? 1.f : -1.f;
    bool  diag = (bi == bj);
    float tsum = 0.f;
#pragma unroll
    for (int i = 0; i < 4; ++i)
#pragma unroll
        for (int j = 0; j < 4; ++j)
#pragma unroll
            for (int r = 0; r < 4; ++r) {
                float L2 = sqi[i][r] + sqj[j] - 2.f * acc[i][j][r];
                L2 = fmaxf(L2, 0.f);
                float u   = __expf(-L2 * cc);
                float u2  = u * u;
                float u4  = u2 * u2;
                float u8  = u4 * u4;
                float u16 = u8 * u8;
                float w = 2.f;
                if (diag) {
                    int gi = gi0 + i * 16 + r, gj = gj0 + j * 16;
                    w = (gi < gj) ? 2.f : ((gi == gj) ? 1.f : 0.f);
                }
                tsum += w * (u + u2 + u4 + u8 + u16);
            }
    tsum *= sgn;

#pragma unroll
    for (int off = 32; off; off >>= 1) tsum += __shfl_down(tsum, off, 64);
    if (lane == 0) wred[wid] = (double)tsum;
    __syncthreads();
    if (t == 0) atomicAdd(acc_out, wred[0] + wred[1] + wred[2] + wred[3]);
}

__global__ void finalize_loss(const double* __restrict__ acc, float* __restrict__ out) {
    if (threadIdx.x == 0 && blockIdx.x == 0)
        out[0] = (float)(*acc / ((double)HALF * (double)HALF));
}

extern "C" void kernel_launch(void* const* d_in, const int* in_sizes, int n_in,
                              void* d_out, int out_size, void* d_ws, size_t ws_size,
                              hipStream_t stream) {
    const float* x = (const float*)d_in[0];   // label / genre_label unused by reference

    double*         d_sumsq  = (double*)d_ws;
    double*         d_acc    = (double*)d_ws + 1;
    float*          d_colsum = (float*)((char*)d_ws + 16);
    float*          d_invc   = (float*)((char*)d_ws + 784);
    float*          d_sq     = (float*)((char*)d_ws + 800);
    unsigned short* d_xb     = (unsigned short*)((char*)d_ws + 33568);

    hipMemsetAsync(d_ws, 0, 800, stream);   // zero accumulators

    row_stats<<<N_TOTAL / 32, 256, 0, stream>>>(x, d_sq, d_colsum, d_sumsq);
    convert_bf16<<<(N_TOTAL * (EMBED / 8)) / 256, 256, 0, stream>>>(x, d_xb);
    finalize_bw<<<1, 1, 0, stream>>>(d_colsum, d_sumsq, d_invc);
    mmd_mfma<<<NBLK, 256, 0, stream>>>(d_xb, d_sq, d_invc, d_acc);
    finalize_loss<<<1, 1, 0, stream>>>(d_acc, (float*)d_out);
}